// Round 6
// baseline (117.394 us; speedup 1.0000x reference)
//
#include <hip/hip_runtime.h>
#include <stdint.h>

// FlagBagEncoder: out[t,:] = mean over {k : flags[t,k] > 0.5} of W[k,:], zeros if empty.
// T=100000, K=512, D=64, fp32 in/out.
//
// v6 DIAGNOSTIC: v5 structure, but the whole algorithm (flag stream -> mask ->
// MFMA -> store) runs NREP=3 times per launch, with flag/out base pointers
// laundered through inline asm each rep (defeats LICM/CSE/DSE -> real re-reads).
// Purpose: at ~150 us this dispatch finally outranks the harness's 800-MB fills
// in the top-5 counter table, giving us FETCH_SIZE / hbm_gbps / VALUBusy /
// MfmaUtil / Occupancy for the actual kernel. Output is identical each rep.

#define T_ROWS 100000
#define K_FLAGS 512
#define D_DIM 64
#define TILES (T_ROWS / 16)   // 6250, exact

typedef __attribute__((ext_vector_type(4))) float f32x4;
typedef __attribute__((ext_vector_type(8))) short bf16x8;

__device__ __forceinline__ uint32_t f32_to_bf16_rne(float f) {
  union { float f; uint32_t u; } v; v.f = f;
  uint32_t u = v.u;
  return (u + 0x7FFFu + ((u >> 16) & 1u)) >> 16;
}

__global__ __launch_bounds__(512, 4) void flagbag_kernel(const float* __restrict__ flags,
                                                         const float* __restrict__ W,
                                                         float* __restrict__ out,
                                                         int nrep) {
  __shared__ uint4 sB[16 * 4 * 64];     // 64 KB fragment table
  __shared__ uint32_t sM[8][256];       // 1 KB/wave mask exchange

  const int tid = threadIdx.x;

  // ---- per-block W -> bf16 fragment table (k = 128*kq + 8*s + e) ----
#pragma unroll
  for (int p = 0; p < 8; ++p) {
    const int E  = tid + p * 512;
    const int s  = E >> 8;
    const int nt = (E >> 6) & 3;
    const int ln = E & 63;
    const int n  = (ln & 15) + 16 * nt;
    const int kq = ln >> 4;
    const int kb = 128 * kq + 8 * s;
    uint32_t r[4];
#pragma unroll
    for (int j = 0; j < 4; ++j) {
      uint32_t lo = f32_to_bf16_rne(W[(size_t)(kb + 2 * j    ) * D_DIM + n]);
      uint32_t hi = f32_to_bf16_rne(W[(size_t)(kb + 2 * j + 1) * D_DIM + n]);
      r[j] = lo | (hi << 16);
    }
    sB[E] = make_uint4(r[0], r[1], r[2], r[3]);
  }
  __syncthreads();

  const int lane = tid & 63;
  const int wave = tid >> 6;
  const int tile = blockIdx.x * 8 + wave;
  if (tile >= TILES) return;

  const int t0 = tile * 16;
  const int m  = lane & 15;
  const int kq = lane >> 4;
  const int mj = m >> 2, mb = m & 3;
  uint32_t* sMw = sM[wave];
  const uint8_t* sMb = reinterpret_cast<const uint8_t*>(sMw);
  const uint4* sbl = &sB[lane];

  uint64_t fb = (uint64_t)flags;
  uint64_t ob = (uint64_t)out;

#pragma unroll 1
  for (int rep = 0; rep < nrep; ++rep) {
    asm volatile("" : "+s"(fb));   // opaque each rep: forces real re-reads
    asm volatile("" : "+s"(ob));   // and real re-writes
    const float* F = (const float*)fb;
    float* O = (float*)ob;

    // ---- phase L: row-sequential contiguous read of the 32-KB tile ----
    const float* ft = F + (size_t)t0 * K_FLAGS + lane * 8;
    uint32_t D0 = 0, D1 = 0, D2 = 0, D3 = 0;
    f32x4 ra[4], rb[4];
#pragma unroll
    for (int r = 0; r < 3; ++r) {
      ra[r] = *reinterpret_cast<const f32x4*>(ft + r * K_FLAGS);
      rb[r] = *reinterpret_cast<const f32x4*>(ft + r * K_FLAGS + 4);
    }
#pragma unroll
    for (int r = 0; r < 16; ++r) {
      if (r + 3 < 16) {
        ra[(r + 3) & 3] = *reinterpret_cast<const f32x4*>(ft + (r + 3) * K_FLAGS);
        rb[(r + 3) & 3] = *reinterpret_cast<const f32x4*>(ft + (r + 3) * K_FLAGS + 4);
      }
      const f32x4 a = ra[r & 3], b = rb[r & 3];
      uint32_t byte = 0;
#pragma unroll
      for (int j = 0; j < 4; ++j) {
        byte |= (a[j] > 0.5f) ? (1u << j)       : 0u;
        byte |= (b[j] > 0.5f) ? (1u << (j + 4)) : 0u;
      }
      const uint32_t sh = byte << ((r & 3) * 8);
      if ((r >> 2) == 0) D0 |= sh;
      else if ((r >> 2) == 1) D1 |= sh;
      else if ((r >> 2) == 2) D2 |= sh;
      else D3 |= sh;
    }

    sMw[0 * 64 + (lane ^ 0)]  = D0;
    sMw[1 * 64 + (lane ^ 4)]  = D1;
    sMw[2 * 64 + (lane ^ 8)]  = D2;
    sMw[3 * 64 + (lane ^ 12)] = D3;

    // ---- phase M: MFMA over the exchanged mask ----
    uint32_t mbytes[16];
#pragma unroll
    for (int s = 0; s < 16; ++s)
      mbytes[s] = sMb[(size_t)(mj * 64 + ((16 * kq + s) ^ (4 * mj))) * 4 + mb];

    int cnt = 0;
#pragma unroll
    for (int s = 0; s < 16; ++s) cnt += __popc(mbytes[s]);
    cnt += __shfl_xor(cnt, 16);
    cnt += __shfl_xor(cnt, 32);
    const float inv = (cnt > 0) ? (1.0f / (float)cnt) : 0.0f;

    f32x4 acc[4];
#pragma unroll
    for (int nt = 0; nt < 4; ++nt) acc[nt] = (f32x4){0.f, 0.f, 0.f, 0.f};

    uint4 bc[4], bn[4];
#pragma unroll
    for (int nt = 0; nt < 4; ++nt) bc[nt] = sbl[nt * 64];

#pragma unroll
    for (int s = 0; s < 16; ++s) {
      if (s + 1 < 16) {
#pragma unroll
        for (int nt = 0; nt < 4; ++nt) bn[nt] = sbl[((s + 1) * 4 + nt) * 64];
      }
      const uint32_t byte = mbytes[s];
      bf16x8 af;
#pragma unroll
      for (int e = 0; e < 8; ++e) af[e] = ((byte >> e) & 1u) ? (short)0x3F80 : (short)0;

#pragma unroll
      for (int nt = 0; nt < 4; ++nt)
        acc[nt] = __builtin_amdgcn_mfma_f32_16x16x32_bf16(
            af, *reinterpret_cast<const bf16x8*>(&bc[nt]), acc[nt], 0, 0, 0);

#pragma unroll
      for (int nt = 0; nt < 4; ++nt) bc[nt] = bn[nt];
    }

    // ---- epilogue ----
#pragma unroll
    for (int r = 0; r < 4; ++r) {
      const int row = kq * 4 + r;
      const float invr = __shfl(inv, row);
      float* orow = O + (size_t)(t0 + row) * D_DIM + m;
#pragma unroll
      for (int nt = 0; nt < 4; ++nt)
        orow[16 * nt] = acc[nt][r] * invr;
    }
  }
}

extern "C" void kernel_launch(void* const* d_in, const int* in_sizes, int n_in,
                              void* d_out, int out_size, void* d_ws, size_t ws_size,
                              hipStream_t stream) {
  const float* flags = (const float*)d_in[0];
  const float* W     = (const float*)d_in[1];
  float* out         = (float*)d_out;

  const int blocks = (TILES + 7) / 8;   // 782
  hipLaunchKernelGGL(flagbag_kernel, dim3(blocks), dim3(512), 0, stream, flags, W, out, 3);
}

// Round 7
// 45.689 us; speedup vs baseline: 2.5694x; 2.5694x over previous
//
#include <hip/hip_runtime.h>
#include <stdint.h>

// FlagBagEncoder: out[t,:] = mean over {k : flags[t,k] > 0.5} of W[k,:], zeros if empty.
// T=100000, K=512, D=64, fp32 in/out.
//
// v7: v5 per-wave logic, restructured for occupancy. R6 diagnostic showed the
// kernel is stall-bound (HBM 27%, VALU 23%, MFMA 6%, occupancy 32%, and per-rep
// time identical whether flags stream from HBM or L3). Fix: (1) 1024-thread
// blocks sharing one 64-KB B-table -> LDS 80 KB/block -> 2 blocks/CU = 32
// waves/CU (was 16); VGPR pinned <=64 via __launch_bounds__(1024,8) (v6 used 56).
// (2) grid = exactly 512 blocks (2/CU, single round, no tail); tile =
// wave*512 + blockIdx.x gives every block 12-13 active waves (static balance).

#define T_ROWS 100000
#define K_FLAGS 512
#define D_DIM 64
#define TILES (T_ROWS / 16)   // 6250, exact

typedef __attribute__((ext_vector_type(4))) float f32x4;
typedef __attribute__((ext_vector_type(8))) short bf16x8;

__device__ __forceinline__ uint32_t f32_to_bf16_rne(float f) {
  union { float f; uint32_t u; } v; v.f = f;
  uint32_t u = v.u;
  return (u + 0x7FFFu + ((u >> 16) & 1u)) >> 16;
}

__global__ __launch_bounds__(1024, 8) void flagbag_kernel(const float* __restrict__ flags,
                                                          const float* __restrict__ W,
                                                          float* __restrict__ out) {
  __shared__ uint4 sB[16 * 4 * 64];     // 64 KB fragment table (all of W, bf16)
  __shared__ uint32_t sM[16][256];      // 1 KB per wave mask exchange

  const int tid = threadIdx.x;

  // ---- per-block W -> bf16 fragment table (k = 128*kq + 8*s + e) ----
#pragma unroll
  for (int p = 0; p < 4; ++p) {
    const int E  = tid + p * 1024;
    const int s  = E >> 8;
    const int nt = (E >> 6) & 3;
    const int ln = E & 63;
    const int n  = (ln & 15) + 16 * nt;
    const int kq = ln >> 4;
    const int kb = 128 * kq + 8 * s;
    uint32_t r[4];
#pragma unroll
    for (int j = 0; j < 4; ++j) {
      uint32_t lo = f32_to_bf16_rne(W[(size_t)(kb + 2 * j    ) * D_DIM + n]);
      uint32_t hi = f32_to_bf16_rne(W[(size_t)(kb + 2 * j + 1) * D_DIM + n]);
      r[j] = lo | (hi << 16);
    }
    sB[E] = make_uint4(r[0], r[1], r[2], r[3]);
  }
  __syncthreads();   // only block-wide barrier

  const int lane = tid & 63;
  const int wave = tid >> 6;
  const int tile = wave * 512 + (int)blockIdx.x;   // grid = 512 blocks exactly
  if (tile >= TILES) return;

  const int t0 = tile * 16;

  // ---- phase L: row-sequential contiguous read of the 32-KB tile ----
  const float* ft = flags + (size_t)t0 * K_FLAGS + lane * 8;

  uint32_t D0 = 0, D1 = 0, D2 = 0, D3 = 0;   // rows 0-3 / 4-7 / 8-11 / 12-15
  f32x4 ra[4], rb[4];
#pragma unroll
  for (int r = 0; r < 3; ++r) {
    ra[r] = *reinterpret_cast<const f32x4*>(ft + r * K_FLAGS);
    rb[r] = *reinterpret_cast<const f32x4*>(ft + r * K_FLAGS + 4);
  }
#pragma unroll
  for (int r = 0; r < 16; ++r) {
    if (r + 3 < 16) {   // compile-time under full unroll
      ra[(r + 3) & 3] = *reinterpret_cast<const f32x4*>(ft + (r + 3) * K_FLAGS);
      rb[(r + 3) & 3] = *reinterpret_cast<const f32x4*>(ft + (r + 3) * K_FLAGS + 4);
    }
    const f32x4 a = ra[r & 3], b = rb[r & 3];
    uint32_t byte = 0;
#pragma unroll
    for (int j = 0; j < 4; ++j) {
      byte |= (a[j] > 0.5f) ? (1u << j)       : 0u;
      byte |= (b[j] > 0.5f) ? (1u << (j + 4)) : 0u;
    }
    const uint32_t sh = byte << ((r & 3) * 8);
    if ((r >> 2) == 0) D0 |= sh;
    else if ((r >> 2) == 1) D1 |= sh;
    else if ((r >> 2) == 2) D2 |= sh;
    else D3 |= sh;
  }

  uint32_t* sMw = sM[wave];
  sMw[0 * 64 + (lane ^ 0)]  = D0;
  sMw[1 * 64 + (lane ^ 4)]  = D1;
  sMw[2 * 64 + (lane ^ 8)]  = D2;
  sMw[3 * 64 + (lane ^ 12)] = D3;
  // wave-internal LDS write->read: compiler inserts the lgkmcnt wait.

  // ---- phase M: MFMA over the exchanged mask ----
  const int m  = lane & 15;   // A row within tile / output col within n-tile
  const int kq = lane >> 4;
  const int mj = m >> 2, mb = m & 3;
  const uint8_t* sMb = reinterpret_cast<const uint8_t*>(sMw);

  uint32_t mbytes[16];
#pragma unroll
  for (int s = 0; s < 16; ++s)
    mbytes[s] = sMb[(size_t)(mj * 64 + ((16 * kq + s) ^ (4 * mj))) * 4 + mb];

  int cnt = 0;
#pragma unroll
  for (int s = 0; s < 16; ++s) cnt += __popc(mbytes[s]);
  cnt += __shfl_xor(cnt, 16);
  cnt += __shfl_xor(cnt, 32);
  const float inv = (cnt > 0) ? (1.0f / (float)cnt) : 0.0f;

  const uint4* sbl = &sB[lane];
  f32x4 acc[4];
#pragma unroll
  for (int nt = 0; nt < 4; ++nt) acc[nt] = (f32x4){0.f, 0.f, 0.f, 0.f};

  uint4 bc[4], bn[4];
#pragma unroll
  for (int nt = 0; nt < 4; ++nt) bc[nt] = sbl[nt * 64];

#pragma unroll
  for (int s = 0; s < 16; ++s) {
    if (s + 1 < 16) {
#pragma unroll
      for (int nt = 0; nt < 4; ++nt) bn[nt] = sbl[((s + 1) * 4 + nt) * 64];
    }
    const uint32_t byte = mbytes[s];
    bf16x8 af;
#pragma unroll
    for (int e = 0; e < 8; ++e) af[e] = ((byte >> e) & 1u) ? (short)0x3F80 : (short)0;

#pragma unroll
    for (int nt = 0; nt < 4; ++nt)
      acc[nt] = __builtin_amdgcn_mfma_f32_16x16x32_bf16(
          af, *reinterpret_cast<const bf16x8*>(&bc[nt]), acc[nt], 0, 0, 0);

#pragma unroll
    for (int nt = 0; nt < 4; ++nt) bc[nt] = bn[nt];
  }

  // ---- epilogue: C/D layout col = lane&15, row = kq*4 + reg ----
#pragma unroll
  for (int r = 0; r < 4; ++r) {
    const int row = kq * 4 + r;
    const float invr = __shfl(inv, row);   // lane 'row' holds that row's count
    float* orow = out + (size_t)(t0 + row) * D_DIM + m;
#pragma unroll
    for (int nt = 0; nt < 4; ++nt)
      orow[16 * nt] = acc[nt][r] * invr;
  }
}

extern "C" void kernel_launch(void* const* d_in, const int* in_sizes, int n_in,
                              void* d_out, int out_size, void* d_ws, size_t ws_size,
                              hipStream_t stream) {
  const float* flags = (const float*)d_in[0];
  const float* W     = (const float*)d_in[1];
  float* out         = (float*)d_out;

  hipLaunchKernelGGL(flagbag_kernel, dim3(512), dim3(1024), 0, stream, flags, W, out);
}

// Round 8
// 42.951 us; speedup vs baseline: 2.7332x; 1.0638x over previous
//
#include <hip/hip_runtime.h>
#include <stdint.h>

// FlagBagEncoder: out[t,:] = mean over {k : flags[t,k] > 0.5} of W[k,:], zeros if empty.
// T=100000, K=512, D=64, fp32 in/out.
//
// v8: v7 (1024-thr blocks, 32 waves/CU, grid 512, tile = wave*512 + bid) with
// PHASE REORDER: the flag stream (phase L) now runs FIRST -- the 205-MB critical
// read starts at cycle ~0 instead of after the W->sB conversion (+ syncthreads)
// prologue that serialized kernel startup in v7. Each wave: phase L (32-KB
// contiguous stream -> mask bits -> sM), then its 1/16 share of W->sB staging,
// one __syncthreads, then phase M (LDS B-table + MFMA) and epilogue.
// k-map (identical for A and B, permutation cancels): k = 128*kq + 8*s + e.

#define T_ROWS 100000
#define K_FLAGS 512
#define D_DIM 64
#define TILES (T_ROWS / 16)   // 6250, exact

typedef __attribute__((ext_vector_type(4))) float f32x4;
typedef __attribute__((ext_vector_type(8))) short bf16x8;

__device__ __forceinline__ uint32_t f32_to_bf16_rne(float f) {
  union { float f; uint32_t u; } v; v.f = f;
  uint32_t u = v.u;
  return (u + 0x7FFFu + ((u >> 16) & 1u)) >> 16;
}

__global__ __launch_bounds__(1024, 8) void flagbag_kernel(const float* __restrict__ flags,
                                                          const float* __restrict__ W,
                                                          float* __restrict__ out) {
  __shared__ uint4 sB[16 * 4 * 64];     // 64 KB fragment table (all of W, bf16)
  __shared__ uint32_t sM[16][256];      // 1 KB per wave mask exchange

  const int tid  = threadIdx.x;
  const int lane = tid & 63;
  const int wave = tid >> 6;
  const int tile = wave * 512 + (int)blockIdx.x;   // grid = 512 blocks exactly
  const bool active = (tile < TILES);
  const int t0 = tile * 16;

  // ---- phase L FIRST: row-sequential contiguous read of the 32-KB tile ----
  if (active) {
    const float* ft = flags + (size_t)t0 * K_FLAGS + lane * 8;

    uint32_t D0 = 0, D1 = 0, D2 = 0, D3 = 0;   // rows 0-3 / 4-7 / 8-11 / 12-15
    f32x4 ra[4], rb[4];
#pragma unroll
    for (int r = 0; r < 3; ++r) {
      ra[r] = *reinterpret_cast<const f32x4*>(ft + r * K_FLAGS);
      rb[r] = *reinterpret_cast<const f32x4*>(ft + r * K_FLAGS + 4);
    }
#pragma unroll
    for (int r = 0; r < 16; ++r) {
      if (r + 3 < 16) {   // compile-time under full unroll
        ra[(r + 3) & 3] = *reinterpret_cast<const f32x4*>(ft + (r + 3) * K_FLAGS);
        rb[(r + 3) & 3] = *reinterpret_cast<const f32x4*>(ft + (r + 3) * K_FLAGS + 4);
      }
      const f32x4 a = ra[r & 3], b = rb[r & 3];
      uint32_t byte = 0;
#pragma unroll
      for (int j = 0; j < 4; ++j) {
        byte |= (a[j] > 0.5f) ? (1u << j)       : 0u;
        byte |= (b[j] > 0.5f) ? (1u << (j + 4)) : 0u;
      }
      const uint32_t sh = byte << ((r & 3) * 8);
      if ((r >> 2) == 0) D0 |= sh;
      else if ((r >> 2) == 1) D1 |= sh;
      else if ((r >> 2) == 2) D2 |= sh;
      else D3 |= sh;
    }

    uint32_t* sMw = sM[wave];
    sMw[0 * 64 + (lane ^ 0)]  = D0;
    sMw[1 * 64 + (lane ^ 4)]  = D1;
    sMw[2 * 64 + (lane ^ 8)]  = D2;
    sMw[3 * 64 + (lane ^ 12)] = D3;
  }

  // ---- W -> bf16 fragment table (k = 128*kq + 8*s + e); overlaps other waves' streams ----
#pragma unroll
  for (int p = 0; p < 4; ++p) {
    const int E  = tid + p * 1024;
    const int s  = E >> 8;
    const int nt = (E >> 6) & 3;
    const int ln = E & 63;
    const int n  = (ln & 15) + 16 * nt;
    const int kq = ln >> 4;
    const int kb = 128 * kq + 8 * s;
    uint32_t r[4];
#pragma unroll
    for (int j = 0; j < 4; ++j) {
      uint32_t lo = f32_to_bf16_rne(W[(size_t)(kb + 2 * j    ) * D_DIM + n]);
      uint32_t hi = f32_to_bf16_rne(W[(size_t)(kb + 2 * j + 1) * D_DIM + n]);
      r[j] = lo | (hi << 16);
    }
    sB[E] = make_uint4(r[0], r[1], r[2], r[3]);
  }
  __syncthreads();   // only block-wide barrier (also orders sM for phase M)

  if (!active) return;

  // ---- phase M: MFMA over the exchanged mask ----
  const int m  = lane & 15;   // A row within tile / output col within n-tile
  const int kq = lane >> 4;
  const int mj = m >> 2, mb = m & 3;
  const uint8_t* sMb = reinterpret_cast<const uint8_t*>(sM[wave]);

  uint32_t mbytes[16];
#pragma unroll
  for (int s = 0; s < 16; ++s)
    mbytes[s] = sMb[(size_t)(mj * 64 + ((16 * kq + s) ^ (4 * mj))) * 4 + mb];

  int cnt = 0;
#pragma unroll
  for (int s = 0; s < 16; ++s) cnt += __popc(mbytes[s]);
  cnt += __shfl_xor(cnt, 16);
  cnt += __shfl_xor(cnt, 32);
  const float inv = (cnt > 0) ? (1.0f / (float)cnt) : 0.0f;

  const uint4* sbl = &sB[lane];
  f32x4 acc[4];
#pragma unroll
  for (int nt = 0; nt < 4; ++nt) acc[nt] = (f32x4){0.f, 0.f, 0.f, 0.f};

  uint4 bc[4], bn[4];
#pragma unroll
  for (int nt = 0; nt < 4; ++nt) bc[nt] = sbl[nt * 64];

#pragma unroll
  for (int s = 0; s < 16; ++s) {
    if (s + 1 < 16) {
#pragma unroll
      for (int nt = 0; nt < 4; ++nt) bn[nt] = sbl[((s + 1) * 4 + nt) * 64];
    }
    const uint32_t byte = mbytes[s];
    bf16x8 af;
#pragma unroll
    for (int e = 0; e < 8; ++e) af[e] = ((byte >> e) & 1u) ? (short)0x3F80 : (short)0;

#pragma unroll
    for (int nt = 0; nt < 4; ++nt)
      acc[nt] = __builtin_amdgcn_mfma_f32_16x16x32_bf16(
          af, *reinterpret_cast<const bf16x8*>(&bc[nt]), acc[nt], 0, 0, 0);

#pragma unroll
    for (int nt = 0; nt < 4; ++nt) bc[nt] = bn[nt];
  }

  // ---- epilogue: C/D layout col = lane&15, row = kq*4 + reg ----
#pragma unroll
  for (int r = 0; r < 4; ++r) {
    const int row = kq * 4 + r;
    const float invr = __shfl(inv, row);   // lane 'row' holds that row's count
    float* orow = out + (size_t)(t0 + row) * D_DIM + m;
#pragma unroll
    for (int nt = 0; nt < 4; ++nt)
      orow[16 * nt] = acc[nt][r] * invr;
  }
}

extern "C" void kernel_launch(void* const* d_in, const int* in_sizes, int n_in,
                              void* d_out, int out_size, void* d_ws, size_t ws_size,
                              hipStream_t stream) {
  const float* flags = (const float*)d_in[0];
  const float* W     = (const float*)d_in[1];
  float* out         = (float*)d_out;

  hipLaunchKernelGGL(flagbag_kernel, dim3(512), dim3(1024), 0, stream, flags, W, out);
}